// Round 8
// baseline (468.701 us; speedup 1.0000x reference)
//
#include <hip/hip_runtime.h>

// Problem constants (from reference)
#define CC 252
#define NSTEPS 232        // C - SCAN_LEN_OFFSET
#define OUTC 484          // 2*NSTEPS + 20
#define NROWS (128 * 1024)
#define ROW_F4 121        // output row = 484 floats = 121 float4

#define INITIAL_DELTA 0.1f
#define DELTA_LOW 0.02f
#define DELTA_HIGH 0.1f

// Scan NV float4 (4*NV steps), packing up/dn bits into uw/dw.
template<int NV>
__device__ __forceinline__ void scan_vecs(const float4* xv, unsigned& uw, unsigned& dw,
                                          float& dc, float& delta, float& tc, float& ntc)
{
    uw = 0u; dw = 0u;
    #pragma unroll
    for (int k = 0; k < NV; ++k) {
        float xs[4] = {xv[k].x, xv[k].y, xv[k].z, xv[k].w};
        #pragma unroll
        for (int j = 0; j < 4; ++j) {
            float xi = xs[j];
            bool up = xi > dc + delta;
            bool dn = xi < dc - delta;
            bool trig = up || dn;
            tc  = trig ? tc + 1.0f : 0.0f;
            ntc = trig ? 0.0f : ntc + 1.0f;
            delta = (tc  >= 3.0f) ? DELTA_LOW  : delta;
            delta = (ntc >= 3.0f) ? DELTA_HIGH : delta;
            dc = trig ? xi : dc;
            uw |= (up ? 1u : 0u) << (k * 4 + j);
            dw |= (dn ? 1u : 0u) << (k * 4 + j);
        }
    }
}

// Expand 4 bits starting at s into a float4 of 0.0/1.0
__device__ __forceinline__ float4 nib4(unsigned w, int s)
{
    return make_float4((float)((w >> s) & 1u),
                       (float)((w >> (s + 1)) & 1u),
                       (float)((w >> (s + 2)) & 1u),
                       (float)((w >> (s + 3)) & 1u));
}

__global__ __launch_bounds__(256) void DeltaModulator_kernel(
    const float* __restrict__ x, float* __restrict__ out)
{
    const int t = threadIdx.x;
    const int lane = t & 63;
    const int wrow0 = blockIdx.x * 256 + (t >> 6) * 64;  // wave's first row
    const int row = wrow0 + lane;                        // this thread's row

    const float4* __restrict__ x4 =
        reinterpret_cast<const float4*>(x + (size_t)row * CC);
    float4* __restrict__ ow =
        reinterpret_cast<float4*>(out) + (size_t)wrow0 * ROW_F4; // wave's out base

    float dc = 0.0f, delta = INITIAL_DELTA, tc = 0.0f, ntc = 0.0f;

    // lane roles for the wave-coalesced chunk stores:
    // store instr i covers rows i*8..i*8+7, each 8 float4 (128B contiguous)
    const int f4i = lane & 7;     // which float4 within the row's chunk segment
    const int rb  = lane >> 3;    // which of the 8 rows in this instr
    const int s4  = f4i * 4;      // bit offset of this float4's nibble

    float4 bA[8], bB[8];
    #pragma unroll
    for (int k = 0; k < 8; ++k) bA[k] = x4[k];   // preload chunk 0

    // 7 full chunks of 32 steps; prefetch next chunk, scan, then immediately
    // store this chunk's UP/DN output wave-coalesced. Reads and writes
    // interleave throughout -> phases overlap by construction. No LDS/barriers.
    #pragma unroll
    for (int ch = 0; ch < 7; ++ch) {
        const float4* cur = (ch & 1) ? bB : bA;
        float4* nxt = (ch & 1) ? bA : bB;
        if (ch < 6) {
            #pragma unroll
            for (int k = 0; k < 8; ++k) nxt[k] = x4[(ch + 1) * 8 + k];
        } else {
            #pragma unroll
            for (int k = 0; k < 7; ++k) nxt[k] = x4[56 + k];  // tail: vecs 56..62
        }

        unsigned uw, dw;
        scan_vecs<8>(cur, uw, dw, dc, delta, tc, ntc);

        // UP: row f4s ch*8 .. ch*8+7
        #pragma unroll
        for (int i = 0; i < 8; ++i) {
            const int sr = i * 8 + rb;
            const unsigned wu = (unsigned)__shfl((int)uw, sr, 64);
            ow[(size_t)sr * ROW_F4 + ch * 8 + f4i] = nib4(wu, s4);
        }
        // DN: row f4s 58 + ch*8 .. +7
        #pragma unroll
        for (int i = 0; i < 8; ++i) {
            const int sr = i * 8 + rb;
            const unsigned wd = (unsigned)__shfl((int)dw, sr, 64);
            ow[(size_t)sr * ROW_F4 + 58 + ch * 8 + f4i] = nib4(wd, s4);
        }
    }

    // Tail chunk: data in bB (prefetched at ch==6). Steps 224..231 = bB[0..1].
    {
        unsigned uw, dw;
        scan_vecs<2>(bB, uw, dw, dc, delta, tc, ntc);

        // UP f4 56,57 ; DN f4 114,115 — 2 instrs each, 32 rows x 32B per instr
        const int tf  = lane & 1;
        const int trb = lane >> 1;
        const int ts  = tf * 4;
        #pragma unroll
        for (int i = 0; i < 2; ++i) {
            const int sr = i * 32 + trb;
            const unsigned wu = (unsigned)__shfl((int)uw, sr, 64);
            ow[(size_t)sr * ROW_F4 + 56 + tf] = nib4(wu, ts);
            const unsigned wd = (unsigned)__shfl((int)dw, sr, 64);
            ow[(size_t)sr * ROW_F4 + 114 + tf] = nib4(wd, ts);
        }

        // extras: x[row, 232:252] = bB[2..6], per-lane own row (80B burst)
        float4* __restrict__ orow =
            reinterpret_cast<float4*>(out) + (size_t)row * ROW_F4;
        #pragma unroll
        for (int k = 0; k < 5; ++k) orow[116 + k] = bB[2 + k];
    }
}

extern "C" void kernel_launch(void* const* d_in, const int* in_sizes, int n_in,
                              void* d_out, int out_size, void* d_ws, size_t ws_size,
                              hipStream_t stream) {
    const float* x = (const float*)d_in[0];
    float* out = (float*)d_out;
    const int threads = 256;
    const int blocks = NROWS / threads; // 512
    DeltaModulator_kernel<<<blocks, threads, 0, stream>>>(x, out);
}

// Round 9
// 358.638 us; speedup vs baseline: 1.3069x; 1.3069x over previous
//
#include <hip/hip_runtime.h>

// Problem constants (from reference)
#define CC 252
#define NSTEPS 232        // C - SCAN_LEN_OFFSET
#define OUTC 484          // 2*NSTEPS + 20
#define NROWS (128 * 1024)
#define ROWS_PER_BLOCK 64 // one wave per block
#define ROW_F4_OUT 121    // output row = 484 floats = 121 float4

#define INITIAL_DELTA 0.1f
#define DELTA_LOW 0.02f
#define DELTA_HIGH 0.1f

#define BITS_STRIDE 17    // u32 per row (16 words + 1 pad) -> 2-way max, free
#define EXTRA_STRIDE 21   // floats per row (20 + 1 pad), odd stride

// Scan NV float4 (4*NV steps), packing up/dn bits into uw/dw.
template<int NV>
__device__ __forceinline__ void scan_vecs(const float4* xv, unsigned& uw, unsigned& dw,
                                          float& dc, float& delta, float& tc, float& ntc)
{
    uw = 0u; dw = 0u;
    #pragma unroll
    for (int k = 0; k < NV; ++k) {
        float xs[4] = {xv[k].x, xv[k].y, xv[k].z, xv[k].w};
        #pragma unroll
        for (int j = 0; j < 4; ++j) {
            float xi = xs[j];
            bool up = xi > dc + delta;
            bool dn = xi < dc - delta;
            bool trig = up || dn;
            tc  = trig ? tc + 1.0f : 0.0f;
            ntc = trig ? 0.0f : ntc + 1.0f;
            delta = (tc  >= 3.0f) ? DELTA_LOW  : delta;
            delta = (ntc >= 3.0f) ? DELTA_HIGH : delta;
            dc = trig ? xi : dc;
            uw |= (up ? 1u : 0u) << (k * 4 + j);
            dw |= (dn ? 1u : 0u) << (k * 4 + j);
        }
    }
}

__global__ __launch_bounds__(64, 4) void DeltaModulator_kernel(
    const float* __restrict__ x, float* __restrict__ out)
{
    __shared__ unsigned bits_lds[ROWS_PER_BLOCK * BITS_STRIDE];   // 4352 B
    __shared__ float    extra_lds[ROWS_PER_BLOCK * EXTRA_STRIDE]; // 5376 B
    // total 9728 B -> 16 blocks/CU (LDS-limited), 16 waves/CU

    const int l = threadIdx.x;                 // lane 0..63
    const int row0 = blockIdx.x * ROWS_PER_BLOCK;
    const int row = row0 + l;

    // ============ Phase A: per-lane scan with ping-pong prefetch ============
    {
        const float4* __restrict__ x4 =
            reinterpret_cast<const float4*>(x + (size_t)row * CC);

        float dc = 0.0f, delta = INITIAL_DELTA, tc = 0.0f, ntc = 0.0f;
        unsigned* __restrict__ myb = &bits_lds[l * BITS_STRIDE];

        float4 bA[8], bB[8];
        #pragma unroll
        for (int k = 0; k < 8; ++k) bA[k] = x4[k];   // preload chunk 0

        #pragma unroll
        for (int ch = 0; ch < 7; ++ch) {
            const float4* cur = (ch & 1) ? bB : bA;
            float4* nxt = (ch & 1) ? bA : bB;
            if (ch < 6) {
                #pragma unroll
                for (int k = 0; k < 8; ++k) nxt[k] = x4[(ch + 1) * 8 + k];
            } else {
                #pragma unroll
                for (int k = 0; k < 7; ++k) nxt[k] = x4[56 + k];  // tail vecs 56..62
            }
            unsigned uw, dw;
            scan_vecs<8>(cur, uw, dw, dc, delta, tc, ntc);
            myb[ch]     = uw;   // UP words 0..6
            myb[8 + ch] = dw;   // DN words 8..14
        }

        // Tail: steps 224..231 from bB[0..1] (ch==6 left tail in bB)
        {
            unsigned uw, dw;
            scan_vecs<2>(bB, uw, dw, dc, delta, tc, ntc);
            myb[7]  = uw;
            myb[15] = dw;
        }

        // extras = x[row, 232:252] = bB[2..6] -> LDS (scalar stores, stride 21)
        {
            float* __restrict__ mye = &extra_lds[l * EXTRA_STRIDE];
            #pragma unroll
            for (int i = 0; i < 5; ++i) {
                float4 v = bB[2 + i];
                mye[i * 4 + 0] = v.x;
                mye[i * 4 + 1] = v.y;
                mye[i * 4 + 2] = v.z;
                mye[i * 4 + 3] = v.w;
            }
        }
    }

    __syncthreads();   // single-wave block: compiles to a cheap lgkm wait

    // ========= Phase B: wave-coalesced expansion of this wave's 64 rows =====
    // Region = 64 rows x 121 float4 = 7744 float4. Lane l handles flat index
    // G = i*64 + l, i = 0..120 (121*64 == 7744 exactly). G = r*121 + f.
    float4* __restrict__ o4 = reinterpret_cast<float4*>(out + (size_t)row0 * OUTC);

    int r = 0;
    int f = l;   // l < 121 always

    #pragma unroll 1
    for (int i = 0; i < 121; ++i) {
        float4 w;
        if (f < 116) {
            const int idx   = (f < 58) ? f : f - 58;
            const int wbase = (f < 58) ? 0 : 8;
            const unsigned word = bits_lds[r * BITS_STRIDE + wbase + (idx >> 3)];
            const int s = 4 * (idx & 7);
            w = make_float4((float)((word >> s) & 1u),
                            (float)((word >> (s + 1)) & 1u),
                            (float)((word >> (s + 2)) & 1u),
                            (float)((word >> (s + 3)) & 1u));
        } else {
            const float* e = &extra_lds[r * EXTRA_STRIDE + (f - 116) * 4];
            w = make_float4(e[0], e[1], e[2], e[3]);
        }
        o4[r * ROW_F4_OUT + f] = w;

        // advance G by 64
        f += 64;
        if (f >= 121) { f -= 121; r += 1; }
    }
}

extern "C" void kernel_launch(void* const* d_in, const int* in_sizes, int n_in,
                              void* d_out, int out_size, void* d_ws, size_t ws_size,
                              hipStream_t stream) {
    const float* x = (const float*)d_in[0];
    float* out = (float*)d_out;
    const int threads = 64;
    const int blocks = NROWS / ROWS_PER_BLOCK; // 2048
    DeltaModulator_kernel<<<blocks, threads, 0, stream>>>(x, out);
}